// Round 9
// baseline (318.809 us; speedup 1.0000x reference)
//
#include <hip/hip_runtime.h>
#include <math.h>

#define D64 64
#define NBATCH 8
#define CBAND 2.0f
#define NSLOT 16
#define CHUNK 64                  // codes per LDS chunk (8 KB)
#define NCHUNK 128                // K / CHUNK
#define NV (2 * NCHUNK)           // virtual chunks: sweep A then sweep B

typedef short s16x8 __attribute__((ext_vector_type(8)));   // 8 bf16 (bit pattern)
typedef float f32x4 __attribute__((ext_vector_type(4)));

#define GLOAD16(g, l) __builtin_amdgcn_global_load_lds( \
    (const __attribute__((address_space(1))) unsigned*)(g), \
    (__attribute__((address_space(3))) unsigned*)(l), 16, 0, 0)
#define GLOAD4(g, l) __builtin_amdgcn_global_load_lds( \
    (const __attribute__((address_space(1))) unsigned*)(g), \
    (__attribute__((address_space(3))) unsigned*)(l), 4, 0, 0)

__device__ inline short f2bf(float f) {
  unsigned u = __builtin_bit_cast(unsigned, f);
  unsigned r = (u + 0x7FFFu + ((u >> 16) & 1u)) >> 16;
  return (short)r;
}

// ---------------- c_sq + bf16 convert + workspace zeroing ----------------
__global__ __launch_bounds__(256) void csq_cvt_kernel(
    const float* __restrict__ cb, float* __restrict__ csq,
    short* __restrict__ cbh,
    unsigned int* __restrict__ counts, unsigned int* __restrict__ pcnt,
    double* __restrict__ sse, int K, int Npts) {
  int t = blockIdx.x * blockDim.x + threadIdx.x;
  if (t < NBATCH * K) counts[t] = 0u;
  if (t < Npts) pcnt[t] = 0u;
  if (t == 0) *sse = 0.0;
  int row = t >> 6, lane = t & 63;
  if (row >= K) return;
  float v = cb[(size_t)row * D64 + lane];
  cbh[(size_t)row * D64 + lane] = f2bf(v);
  v *= v;
  #pragma unroll
  for (int off = 32; off; off >>= 1) v += __shfl_xor(v, off, 64);
  if (lane == 0) csq[row] = v;
}

// ---------------- fused filter: sweep A (min) + sweep B (emit) ----------------
// block = 2 waves x 32 points = 64 points, full K, LDS-staged codebook.
// grid = N/64 = 1024 -> 4 independent blocks (barrier domains) per CU.
// 3-deep buffers + counted vmcnt (never 0 in steady state) + raw barriers.
// Every thread issues exactly 5 staging loads per chunk (uniform vmcnt).
__global__ __launch_bounds__(128, 2) void fused_filter_kernel(
    const float* __restrict__ z, const short* __restrict__ cbh,
    const float* __restrict__ csq,
    unsigned int* __restrict__ pcnt, int* __restrict__ cand, int N, int K) {
  __shared__ short lcb[3][CHUNK * D64];     // 3 x 8 KB
  __shared__ float lcsq[3][CHUNK];          // 3 x 256 B

  int w = threadIdx.x >> 6;                 // 0..1
  int l = threadIdx.x & 63;
  int lr = l & 15, lg = l >> 4;
  int base = blockIdx.x * 64 + w * 32;

  // ---- A fragments (z rows) ----
  s16x8 A[2][2];
  #pragma unroll
  for (int rt = 0; rt < 2; ++rt) {
    int row = base + rt * 16 + lr;
    #pragma unroll
    for (int kh = 0; kh < 2; ++kh) {
      const float4* zp = reinterpret_cast<const float4*>(
          z + (size_t)row * D64 + kh * 32 + lg * 8);
      float4 p0 = zp[0], p1 = zp[1];
      s16x8 t;
      t[0] = f2bf(p0.x); t[1] = f2bf(p0.y); t[2] = f2bf(p0.z); t[3] = f2bf(p0.w);
      t[4] = f2bf(p1.x); t[5] = f2bf(p1.y); t[6] = f2bf(p1.z); t[7] = f2bf(p1.w);
      A[rt][kh] = t;
    }
  }

  // per-lane swizzled LDS read offsets (constant over inner iters)
  int sw = (lr & 7) << 4;
  int p0off = ((lr * 128 + lg * 16) ^ sw);
  int p1off = ((lr * 128 + 64 + lg * 16) ^ sw);
  int swl = (l >> 3) << 4;                  // staging source swizzle

  const char* cbbytes = (const char*)cbh;
  // STAGE: 4x GLOAD16 (cbh chunk, pre-swizzled source) + 1x GLOAD4 (csq).
  // both waves duplicate the csq load (same src+dst) for uniform vmcnt.
#define STAGE(chunk, b)                                                       \
  {                                                                           \
    const char* src = cbbytes + (size_t)(chunk) * (CHUNK * 128);              \
    char* dstb = (char*)lcb[b];                                               \
    _Pragma("unroll")                                                         \
    for (int j = 0; j < 4; ++j) {                                             \
      int X = (w * 4 + j) * 1024 + l * 16;                                    \
      GLOAD16(src + (X ^ swl), dstb + (w * 4 + j) * 1024);                    \
    }                                                                         \
    const char* csrc = (const char*)(csq + (chunk) * CHUNK);                  \
    GLOAD4(csrc + l * 4, (char*)lcsq[b]);                                     \
  }

  float rmin[2][4];
  #pragma unroll
  for (int rt = 0; rt < 2; ++rt)
    #pragma unroll
    for (int r = 0; r < 4; ++r) rmin[rt][r] = INFINITY;
  float thr[2][4];

  // compute one virtual chunk out of buffer b
  auto do_chunk = [&](int v, int b) {
    const char* pb0 = (const char*)lcb[b] + p0off;
    const char* pb1 = (const char*)lcb[b] + p1off;
    const float* cqb = lcsq[b] + lr;
    if (v < NCHUNK) {
      // ---- sweep A: accumulate per-point min ----
      #pragma unroll
      for (int i = 0; i < 4; ++i) {
        s16x8 B0 = *(const s16x8*)(pb0 + i * 2048);
        s16x8 B1 = *(const s16x8*)(pb1 + i * 2048);
        float cq = cqb[i * 16];
        #pragma unroll
        for (int rt = 0; rt < 2; ++rt) {
          f32x4 acc = {0.f, 0.f, 0.f, 0.f};
          acc = __builtin_amdgcn_mfma_f32_16x16x32_bf16(A[rt][0], B0, acc, 0, 0, 0);
          acc = __builtin_amdgcn_mfma_f32_16x16x32_bf16(A[rt][1], B1, acc, 0, 0, 0);
          #pragma unroll
          for (int r = 0; r < 4; ++r) {
            float s = fmaf(-2.0f, acc[r], cq);
            rmin[rt][r] = fminf(rmin[rt][r], s);
          }
        }
      }
      if (v == NCHUNK - 1) {
        // reduce over the 16 code-cols (lane bits 0..3) -> per-point threshold
        #pragma unroll
        for (int rt = 0; rt < 2; ++rt)
          #pragma unroll
          for (int r = 0; r < 4; ++r) {
            float x = rmin[rt][r];
            x = fminf(x, __shfl_xor(x, 1, 64));
            x = fminf(x, __shfl_xor(x, 2, 64));
            x = fminf(x, __shfl_xor(x, 4, 64));
            x = fminf(x, __shfl_xor(x, 8, 64));
            thr[rt][r] = x + CBAND;
          }
      }
    } else {
      // ---- sweep B: emit candidates within band ----
      int c = v - NCHUNK;
      #pragma unroll
      for (int i = 0; i < 4; ++i) {
        s16x8 B0 = *(const s16x8*)(pb0 + i * 2048);
        s16x8 B1 = *(const s16x8*)(pb1 + i * 2048);
        float cq = cqb[i * 16];
        float s[2][4];
        #pragma unroll
        for (int rt = 0; rt < 2; ++rt) {
          f32x4 acc = {0.f, 0.f, 0.f, 0.f};
          acc = __builtin_amdgcn_mfma_f32_16x16x32_bf16(A[rt][0], B0, acc, 0, 0, 0);
          acc = __builtin_amdgcn_mfma_f32_16x16x32_bf16(A[rt][1], B1, acc, 0, 0, 0);
          #pragma unroll
          for (int r = 0; r < 4; ++r)
            s[rt][r] = fmaf(-2.0f, acc[r], cq);
        }
        int hits = 0;
        #pragma unroll
        for (int rt = 0; rt < 2; ++rt)
          #pragma unroll
          for (int r = 0; r < 4; ++r)
            hits |= (s[rt][r] <= thr[rt][r]) ? (1 << (rt * 4 + r)) : 0;
        if (__any(hits != 0)) {
          int k = c * CHUNK + i * 16 + lr;
          #pragma unroll
          for (int rt = 0; rt < 2; ++rt)
            #pragma unroll
            for (int r = 0; r < 4; ++r) {
              if (hits & (1 << (rt * 4 + r))) {
                int n = base + rt * 16 + lg * 4 + r;
                unsigned slot = atomicAdd(&pcnt[n], 1u);
                if (slot < NSLOT) cand[(size_t)n * NSLOT + slot] = k;
              }
            }
        }
      }
    }
  };

  // prologue: fill the 3 buffers (vchunks 0,1,2)
  STAGE(0, 0);
  STAGE(1, 1);
  STAGE(2, 2);

  // main loop: vchunks 0..NV-4, staging v+3 each iter.
  // wait vmcnt(10): chunk v's 5 loads done, chunks v+1,v+2 (10) stay in flight.
  for (int v = 0; v < NV - 3; ++v) {
    asm volatile("s_waitcnt vmcnt(10)" ::: "memory");
    __builtin_amdgcn_sched_barrier(0);
    __builtin_amdgcn_s_barrier();
    do_chunk(v, v % 3);
    asm volatile("s_waitcnt lgkmcnt(0)" ::: "memory");
    __builtin_amdgcn_sched_barrier(0);
    __builtin_amdgcn_s_barrier();
    STAGE((v + 3) & (NCHUNK - 1), v % 3);   // vchunk v+3 -> data chunk (v+3)%128
  }
  // epilogue: v = NV-3 (2 chunks in flight), NV-2 (1), NV-1 (0)
  {
    int v = NV - 3;
    asm volatile("s_waitcnt vmcnt(10)" ::: "memory");
    __builtin_amdgcn_sched_barrier(0);
    __builtin_amdgcn_s_barrier();
    do_chunk(v, v % 3);
    asm volatile("s_waitcnt lgkmcnt(0)" ::: "memory");
    __builtin_amdgcn_s_barrier();
  }
  {
    int v = NV - 2;
    asm volatile("s_waitcnt vmcnt(5)" ::: "memory");
    __builtin_amdgcn_sched_barrier(0);
    __builtin_amdgcn_s_barrier();
    do_chunk(v, v % 3);
    asm volatile("s_waitcnt lgkmcnt(0)" ::: "memory");
    __builtin_amdgcn_s_barrier();
  }
  {
    int v = NV - 1;
    asm volatile("s_waitcnt vmcnt(0)" ::: "memory");
    __builtin_amdgcn_sched_barrier(0);
    __builtin_amdgcn_s_barrier();
    do_chunk(v, v % 3);
  }
#undef STAGE
}

// ---- exact fp32 rescore + fp64 tiebreak + counts + index out + quantize ----
__global__ __launch_bounds__(256) void rescore_quant_kernel(
    const float* __restrict__ z, const float* __restrict__ cb,
    const float* __restrict__ csq,
    const unsigned int* __restrict__ pcnt, const int* __restrict__ cand,
    const int* __restrict__ batch_raw,
    float* __restrict__ out_idx, float* __restrict__ outq,
    unsigned int* __restrict__ counts, double* __restrict__ sse,
    int N, int K) {
  __shared__ double red[4];
  int n = blockIdx.x * blockDim.x + threadIdx.x;
  int cnt = min(pcnt[n], (unsigned)NSLOT);

  const float4* z4 = reinterpret_cast<const float4*>(z) + (size_t)n * 16;
  float4 zr[16];
  #pragma unroll
  for (int d = 0; d < 16; ++d) zr[d] = z4[d];

  float b1 = INFINITY, b2 = INFINITY;
  int i1 = 0x7FFFFFFF, i2 = 0x7FFFFFFF;
  for (int c = 0; c < cnt; ++c) {
    int k = cand[(size_t)n * NSLOT + c];
    const float4* cr = reinterpret_cast<const float4*>(cb) + (size_t)k * 16;
    float4 a = {0.f, 0.f, 0.f, 0.f};
    #pragma unroll
    for (int d = 0; d < 16; ++d) {
      float4 q = cr[d], zz = zr[d];
      a.x = fmaf(q.x, zz.x, a.x);
      a.y = fmaf(q.y, zz.y, a.y);
      a.z = fmaf(q.z, zz.z, a.z);
      a.w = fmaf(q.w, zz.w, a.w);
    }
    float s = csq[k] - 2.0f * ((a.x + a.y) + (a.z + a.w));
    // top-2 with (score, index) ordering (candidates arrive unordered)
    bool bet1 = (s < b1) || (s == b1 && k < i1);
    float cs = bet1 ? b1 : s;  int ci = bet1 ? i1 : k;
    b1 = bet1 ? s : b1;        i1 = bet1 ? k : i1;
    bool bet2 = (cs < b2) || (cs == b2 && ci < i2);
    b2 = bet2 ? cs : b2;       i2 = bet2 ? ci : i2;
  }

  int final_i = i1;
  if (cnt >= 2 && (b2 - b1) < 1e-3f) {
    const float* zp  = z  + (size_t)n  * D64;
    const float* c1p = cb + (size_t)i1 * D64;
    const float* c2p = cb + (size_t)i2 * D64;
    double d0 = 0.0, d1 = 0.0;
    for (int d = 0; d < D64; ++d) {
      double t0 = (double)zp[d] - (double)c1p[d];
      double t1 = (double)zp[d] - (double)c2p[d];
      d0 += t0 * t0;
      d1 += t1 * t1;
    }
    if (d1 < d0 || (d1 == d0 && i2 < i1)) final_i = i2;
  }

  out_idx[n] = (float)final_i;

  int is64 = (batch_raw[N - 1] == 0) ? 1 : 0;
  int b = is64 ? batch_raw[2 * n] : batch_raw[n];
  atomicAdd(&counts[(size_t)b * K + final_i], 1u);

  // ---- quantize + straight-through + SSE (z row already in registers) ----
  const float4* cr = reinterpret_cast<const float4*>(cb) + (size_t)final_i * 16;
  float4* oq = reinterpret_cast<float4*>(outq) + (size_t)n * 16;
  double local = 0.0;
  #pragma unroll
  for (int d = 0; d < 16; ++d) {
    float4 q = cr[d], zz = zr[d];
    float4 t = {q.x - zz.x, q.y - zz.y, q.z - zz.z, q.w - zz.w};
    float4 st = {zz.x + t.x, zz.y + t.y, zz.z + t.z, zz.w + t.w};
    oq[d] = st;
    local += (double)t.x * t.x + (double)t.y * t.y +
             (double)t.z * t.z + (double)t.w * t.w;
  }
  #pragma unroll
  for (int off = 32; off; off >>= 1) local += __shfl_xor(local, off, 64);
  int lane = threadIdx.x & 63, wv = threadIdx.x >> 6;
  if (lane == 0) red[wv] = local;
  __syncthreads();
  if (threadIdx.x == 0) atomicAdd(sse, red[0] + red[1] + red[2] + red[3]);
}

// ---------------- per-batch entropy / perplexity / unique ----------------
__global__ __launch_bounds__(256) void stats_kernel(
    const unsigned int* __restrict__ counts,
    double* __restrict__ perp, double* __restrict__ ent,
    double* __restrict__ uniq, int K) {
  __shared__ double sh4[4], she[4], shu[4];
  int b = blockIdx.x;
  const unsigned int* c = counts + (size_t)b * K;
  int lane = threadIdx.x & 63, w = threadIdx.x >> 6;

  double tot = 0.0;
  for (int k = threadIdx.x; k < K; k += blockDim.x) tot += (double)c[k];
  #pragma unroll
  for (int off = 32; off; off >>= 1) tot += __shfl_xor(tot, off, 64);
  if (lane == 0) sh4[w] = tot;
  __syncthreads();
  double total = sh4[0] + sh4[1] + sh4[2] + sh4[3];
  double denom = fmax(total, 1.0);

  double e = 0.0, u = 0.0;
  for (int k = threadIdx.x; k < K; k += blockDim.x) {
    double cc = (double)c[k];
    double p = cc / denom;
    e -= p * log(p + 1e-10);
    if (cc > 0.0) u += 1.0;
  }
  #pragma unroll
  for (int off = 32; off; off >>= 1) {
    e += __shfl_xor(e, off, 64);
    u += __shfl_xor(u, off, 64);
  }
  if (lane == 0) { she[w] = e; shu[w] = u; }
  __syncthreads();
  if (threadIdx.x == 0) {
    double E = she[0] + she[1] + she[2] + she[3];
    double U = shu[0] + shu[1] + shu[2] + shu[3];
    ent[b] = E; perp[b] = exp(E); uniq[b] = U;
  }
}

// ---------------- finalize scalars ----------------
__global__ void final_kernel(const double* __restrict__ sse,
                             const double* __restrict__ perp,
                             const double* __restrict__ ent,
                             const double* __restrict__ uniq,
                             float* __restrict__ out, int N) {
  if (threadIdx.x == 0 && blockIdx.x == 0) {
    double mp = 0.0, me = 0.0, mu = 0.0;
    for (int b = 0; b < NBATCH; ++b) { mp += perp[b]; me += ent[b]; mu += uniq[b]; }
    mp /= NBATCH; me /= NBATCH; mu /= NBATCH;
    double loss = *sse / ((double)N * (double)D64);
    size_t voff = (size_t)N * D64;
    size_t coff = voff + 1;
    size_t poff = coff + 1 + (size_t)N;
    out[voff] = (float)loss;
    out[coff] = (float)loss;
    out[poff] = (float)mp;
    out[poff + 1] = (float)me;
    out[poff + 2] = (float)mu;
  }
}

extern "C" void kernel_launch(void* const* d_in, const int* in_sizes, int n_in,
                              void* d_out, int out_size, void* d_ws, size_t ws_size,
                              hipStream_t stream) {
  const float* z = (const float*)d_in[0];
  const int* bid = (const int*)d_in[1];
  const float* cb = (const float*)d_in[2];
  int N = in_sizes[1];
  int Dd = in_sizes[0] / N;
  int K = in_sizes[2] / Dd;
  float* out = (float*)d_out;

  // workspace layout (256B-aligned chunks)
  char* ws = (char*)d_ws;
  size_t off = 0;
  auto alloc = [&](size_t bytes) {
    void* p = ws + off;
    off += (bytes + 255) & ~(size_t)255;
    return p;
  };
  unsigned int* counts = (unsigned int*)alloc((size_t)NBATCH * K * 4);
  double* sse  = (double*)alloc(8);
  double* perp = (double*)alloc(8 * NBATCH);
  double* ent  = (double*)alloc(8 * NBATCH);
  double* uniq = (double*)alloc(8 * NBATCH);
  float* csq = (float*)alloc((size_t)K * 4);
  short* cbh = (short*)alloc((size_t)K * D64 * 2);
  unsigned int* pcnt = (unsigned int*)alloc((size_t)N * 4);
  int* cand = (int*)alloc((size_t)N * NSLOT * 4);

  size_t ioff = (size_t)N * Dd + 2;

  csq_cvt_kernel<<<(K * 64 + 255) / 256, 256, 0, stream>>>(
      cb, csq, cbh, counts, pcnt, sse, K, N);
  fused_filter_kernel<<<N / 64, 128, 0, stream>>>(z, cbh, csq, pcnt, cand, N, K);
  rescore_quant_kernel<<<N / 256, 256, 0, stream>>>(
      z, cb, csq, pcnt, cand, bid, out + ioff, out, counts, sse, N, K);
  stats_kernel<<<NBATCH, 256, 0, stream>>>(counts, perp, ent, uniq, K);
  final_kernel<<<1, 64, 0, stream>>>(sse, perp, ent, uniq, out, N);
}